// Round 1
// baseline (1199.907 us; speedup 1.0000x reference)
//
#include <hip/hip_runtime.h>
#include <hip/hip_bf16.h>
#include <cstdint>
#include <cstddef>

// Problem constants
#define T_DIM 128
#define B_DIM 64
#define E_DIM 1024
#define H_DIM 1024
#define V_DIM 10000
#define L_DIM 2
#define VP    10112   // V padded to multiple of 128
#define MR    8128    // (T-1)*B valid rows
#define MRP   8192    // padded to multiple of 128

typedef __bf16 bf16_t;
typedef bf16_t bf16x8 __attribute__((ext_vector_type(8)));
typedef float  f32x4  __attribute__((ext_vector_type(4)));

__device__ __forceinline__ void g2l16(const void* g, void* l) {
  __builtin_amdgcn_global_load_lds((const __attribute__((address_space(1))) void*)g,
                                   (__attribute__((address_space(3))) void*)l,
                                   16, 0, 0);
}

__device__ __forceinline__ float fast_tanh(float v) {
  v = fminf(15.f, fmaxf(-15.f, v));
  float e = __expf(2.f * v);
  return (e - 1.f) / (e + 1.f);
}

// C = A @ B^T (+bias[n]) (+Z[(m&63)*1024+n]) (tanh?) ; A: Mp x K bf16, B: Np x K bf16
// outb (bf16, row stride outb_stride) stored for ALL padded rows (scratch buffers only).
// outf (fp32) stored at base + ((m>>6)+t_off)*stride_t + (m&63)*stride_b + n, guarded
// by m < Mvalid && n < Nvalid.
__global__ __launch_bounds__(256)
void gemm_bt(const bf16_t* __restrict__ A, const bf16_t* __restrict__ Bm, int K,
             const float* __restrict__ bias, int Nvalid,
             const float* __restrict__ Z, int do_tanh,
             bf16_t* __restrict__ outb, int outb_stride,
             float* __restrict__ outf, long stride_t, int t_off, int stride_b,
             int Mvalid)
{
  __shared__ alignas(16) bf16_t lA[128 * 32];
  __shared__ alignas(16) bf16_t lB[128 * 32];
  const int tid  = threadIdx.x;
  const int wid  = tid >> 6;
  const int lane = tid & 63;
  const int bm = blockIdx.y, bn = blockIdx.x;

  f32x4 zero = {0.f, 0.f, 0.f, 0.f};
  f32x4 acc[4][4];
#pragma unroll
  for (int i = 0; i < 4; ++i)
#pragma unroll
    for (int j = 0; j < 4; ++j) acc[i][j] = zero;

  // staging: each thread loads one 16B chunk per 64-row half-tile
  const int r0 = tid >> 2;      // 0..63 row within half-tile
  const int c4 = tid & 3;       // which 8-bf16 chunk of the 32-wide K tile
  const bf16_t* gA0 = A  + (size_t)(bm * 128 + r0) * K + c4 * 8;
  const bf16_t* gA1 = gA0 + (size_t)64 * K;
  const bf16_t* gB0 = Bm + (size_t)(bn * 128 + r0) * K + c4 * 8;
  const bf16_t* gB1 = gB0 + (size_t)64 * K;
  char* lAb = (char*)lA;
  char* lBb = (char*)lB;
  // wave-uniform LDS bases: lane i lands at base + i*16 == (row*64 + chunk*16)
  char* ldsA0 = lAb + wid * 1024;
  char* ldsA1 = lAb + 4096 + wid * 1024;
  char* ldsB0 = lBb + wid * 1024;
  char* ldsB1 = lBb + 4096 + wid * 1024;

  const int mrow = (wid >> 1) * 64;   // wave's 64x64 quadrant
  const int ncol = (wid & 1) * 64;
  const int fr = lane & 15;           // fragment row/col within 16
  const int fq = (lane >> 4) * 16;    // byte offset of 8-elem k-chunk

  for (int k0 = 0; k0 < K; k0 += 32) {
    __syncthreads();                  // protect LDS from overwrite
    g2l16(gA0 + k0, ldsA0);
    g2l16(gA1 + k0, ldsA1);
    g2l16(gB0 + k0, ldsB0);
    g2l16(gB1 + k0, ldsB1);
    __syncthreads();                  // compiler drains vmcnt before s_barrier

    bf16x8 af[4], bfv[4];
#pragma unroll
    for (int t = 0; t < 4; ++t) {
      af[t]  = *(const bf16x8*)(lAb + (mrow + t * 16 + fr) * 64 + fq);
      bfv[t] = *(const bf16x8*)(lBb + (ncol + t * 16 + fr) * 64 + fq);
    }
#pragma unroll
    for (int tm = 0; tm < 4; ++tm)
#pragma unroll
      for (int tn = 0; tn < 4; ++tn)
        acc[tm][tn] = __builtin_amdgcn_mfma_f32_16x16x32_bf16(af[tm], bfv[tn], acc[tm][tn], 0, 0, 0);
  }

  // epilogue: C/D layout col=lane&15, row=(lane>>4)*4+reg (m89-verified)
  const int rb = (lane >> 4) * 4;
  const int cb = lane & 15;
#pragma unroll
  for (int tm = 0; tm < 4; ++tm) {
#pragma unroll
    for (int tn = 0; tn < 4; ++tn) {
      const int col = bn * 128 + ncol + tn * 16 + cb;
      const float bv = (col < Nvalid) ? bias[col] : 0.f;
#pragma unroll
      for (int r = 0; r < 4; ++r) {
        const int row = bm * 128 + mrow + tm * 16 + rb + r;
        float v = acc[tm][tn][r] + bv;
        if (Z) v += Z[(row & 63) * 1024 + col];   // Z only used with N=1024
        if (do_tanh) v = fast_tanh(v);
        if (outb) outb[(size_t)row * outb_stride + col] = (bf16_t)v;
        if (outf && row < Mvalid && col < Nvalid) {
          long o = ((long)((row >> 6) + t_off)) * stride_t
                 + (long)(row & 63) * stride_b + col;
          outf[o] = v;
        }
      }
    }
  }
}

// ---- conversion / gather kernels ----
__global__ void k_f32_to_bf16(const float* __restrict__ s, bf16_t* __restrict__ d, int n) {
  int i = blockIdx.x * 256 + threadIdx.x;
  if (i < n) d[i] = (bf16_t)s[i];
}

__global__ void k_cvt_dw(const float* __restrict__ s, bf16_t* __restrict__ d) {
  int i = blockIdx.x * 256 + threadIdx.x;   // over VP*1024
  int r = i >> 10, c = i & 1023;
  float v = (r < V_DIM) ? s[r * 1024 + c] : 0.f;
  d[i] = (bf16_t)v;
}

__global__ void k_gather_rest(const int* __restrict__ inp, const float* __restrict__ etab,
                              bf16_t* __restrict__ X0) {
  size_t i = (size_t)blockIdx.x * 256 + threadIdx.x;  // MRP*1024
  int m = (int)(i >> 10), e = (int)(i & 1023);
  float v = 0.f;
  if (m < MR) {
    int t = (m >> 6) + 1, b = m & 63;
    int idx = inp[t * B_DIM + b];
    v = etab[(size_t)idx * E_DIM + e];
  }
  X0[i] = (bf16_t)v;
}

__global__ void k_gather_first(const int* __restrict__ inp, const float* __restrict__ etab,
                               bf16_t* __restrict__ x0) {
  int i = blockIdx.x * 256 + threadIdx.x;   // 128*1024
  int m = i >> 10, e = i & 1023;
  float v = 0.f;
  if (m < B_DIM) v = etab[(size_t)inp[m] * E_DIM + e];
  x0[i] = (bf16_t)v;
}

__global__ void k_cvt_hidden(const float* __restrict__ hid, bf16_t* __restrict__ d) {
  int i = blockIdx.x * 256 + threadIdx.x;   // L*128*1024
  int l = i >> 17, r = (i >> 10) & 127, e = i & 1023;
  float v = (r < B_DIM) ? hid[(l * B_DIM + r) * H_DIM + e] : 0.f;
  d[i] = (bf16_t)v;
}

extern "C" void kernel_launch(void* const* d_in, const int* in_sizes, int n_in,
                              void* d_out, int out_size, void* d_ws, size_t ws_size,
                              hipStream_t stream) {
  const int*   inp    = (const int*)  d_in[0];
  const float* hidden = (const float*)d_in[1];
  const float* etab   = (const float*)d_in[2];
  const float* Ww     = (const float*)d_in[3];
  const float* Wb     = (const float*)d_in[4];
  const float* Uw     = (const float*)d_in[5];
  const float* Ub     = (const float*)d_in[6];
  const float* Fw     = (const float*)d_in[7];
  const float* Fb     = (const float*)d_in[8];
  const float* Dw     = (const float*)d_in[9];
  const float* Db     = (const float*)d_in[10];
  float* out = (float*)d_out;

  // workspace carve (~86 MB)
  char* p = (char*)d_ws;
  auto carve = [&](size_t n) { char* r = p; p += (n + 255) & ~(size_t)255; return r; };
  bf16_t* Wbf  = (bf16_t*)carve((size_t)L_DIM * H_DIM * E_DIM * 2);
  bf16_t* Ubf  = (bf16_t*)carve((size_t)L_DIM * H_DIM * H_DIM * 2);
  bf16_t* Fbf  = (bf16_t*)carve((size_t)L_DIM * E_DIM * H_DIM * 2);
  bf16_t* Dbf  = (bf16_t*)carve((size_t)VP * H_DIM * 2);
  bf16_t* X0   = (bf16_t*)carve((size_t)MRP * E_DIM * 2);
  bf16_t* Hb   = (bf16_t*)carve((size_t)MRP * H_DIM * 2);
  bf16_t* Xb   = (bf16_t*)carve((size_t)MRP * E_DIM * 2);
  bf16_t* s0   = (bf16_t*)carve((size_t)128 * E_DIM * 2);
  bf16_t* s1   = (bf16_t*)carve((size_t)128 * E_DIM * 2);
  bf16_t* h0b0 = (bf16_t*)carve((size_t)128 * H_DIM * 2);
  bf16_t* h0b1 = (bf16_t*)carve((size_t)128 * H_DIM * 2);
  bf16_t* hidb = (bf16_t*)carve((size_t)L_DIM * 128 * H_DIM * 2);
  float*  HU   = (float*) carve((size_t)B_DIM * H_DIM * 4);
  float*  aU0  = (float*) carve((size_t)B_DIM * H_DIM * 4);
  float*  aU1  = (float*) carve((size_t)B_DIM * H_DIM * 4);

  const int WN = L_DIM * H_DIM * E_DIM;   // 2097152
  k_f32_to_bf16<<<(WN + 255) / 256, 256, 0, stream>>>(Ww, Wbf, WN);
  k_f32_to_bf16<<<(WN + 255) / 256, 256, 0, stream>>>(Uw, Ubf, WN);
  k_f32_to_bf16<<<(WN + 255) / 256, 256, 0, stream>>>(Fw, Fbf, WN);
  k_cvt_dw   <<<(VP * H_DIM) / 256, 256, 0, stream>>>(Dw, Dbf);
  k_gather_rest <<<(MRP * E_DIM) / 256, 256, 0, stream>>>(inp, etab, X0);
  k_gather_first<<<(128 * E_DIM) / 256, 256, 0, stream>>>(inp, etab, s0);
  k_cvt_hidden  <<<(L_DIM * 128 * H_DIM) / 256, 256, 0, stream>>>(hidden, hidb);

  float* hall = out + (size_t)T_DIM * B_DIM * V_DIM;
  const long ST_H = (long)L_DIM * B_DIM * H_DIM;   // 131072
  const long ST_V = (long)B_DIM * V_DIM;           // 640000

  // ---- step 0 (M=64 padded to 128) ----
  bf16_t* xc = s0;
  for (int l = 0; l < L_DIM; ++l) {
    bf16_t* h0b = l ? h0b1 : h0b0;
    float*  aU  = l ? aU1 : aU0;
    bf16_t* xn  = l ? s0 : s1;
    // HU = hidden[l] @ Uw[l]^T + Ub[l]
    gemm_bt<<<dim3(8, 1), 256, 0, stream>>>(hidb + (size_t)l * 128 * H_DIM,
        Ubf + (size_t)l * H_DIM * H_DIM, H_DIM,
        Ub + l * H_DIM, H_DIM, nullptr, 0,
        nullptr, 0, HU, 0L, 0, H_DIM, B_DIM);
    // h0 = tanh(x @ Ww[l]^T + Wb[l] + HU) -> h_all[t=0, l] + bf16
    gemm_bt<<<dim3(8, 1), 256, 0, stream>>>(xc,
        Wbf + (size_t)l * H_DIM * E_DIM, E_DIM,
        Wb + l * H_DIM, H_DIM, HU, 1,
        h0b, H_DIM, hall + (size_t)l * B_DIM * H_DIM, ST_H, 0, H_DIM, B_DIM);
    // aU[l] = h0 @ Uw[l]^T + Ub[l]
    gemm_bt<<<dim3(8, 1), 256, 0, stream>>>(h0b,
        Ubf + (size_t)l * H_DIM * H_DIM, H_DIM,
        Ub + l * H_DIM, H_DIM, nullptr, 0,
        nullptr, 0, aU, 0L, 0, H_DIM, B_DIM);
    // x = tanh(h0 @ Fw[l]^T + Fb[l])
    gemm_bt<<<dim3(8, 1), 256, 0, stream>>>(h0b,
        Fbf + (size_t)l * E_DIM * H_DIM, H_DIM,
        Fb + l * E_DIM, E_DIM, nullptr, 1,
        xn, E_DIM, nullptr, 0L, 0, 0, 0);
    xc = xn;
  }
  // logits0 = x @ Dw^T + Db
  gemm_bt<<<dim3(VP / 128, 1), 256, 0, stream>>>(xc, Dbf, H_DIM,
      Db, V_DIM, nullptr, 0,
      nullptr, 0, out, ST_V, 0, V_DIM, B_DIM);

  // ---- t >= 1 (M=8128 padded to 8192) ----
  bf16_t* Xc = X0;
  for (int l = 0; l < L_DIM; ++l) {
    float* aU = l ? aU1 : aU0;
    // H = tanh(X @ Ww[l]^T + Wb[l] + aU[l]) -> h_all[t, l] + bf16
    gemm_bt<<<dim3(8, MRP / 128), 256, 0, stream>>>(Xc,
        Wbf + (size_t)l * H_DIM * E_DIM, E_DIM,
        Wb + l * H_DIM, H_DIM, aU, 1,
        Hb, H_DIM, hall + (size_t)l * B_DIM * H_DIM, ST_H, 1, H_DIM, MR);
    // X = tanh(H @ Fw[l]^T + Fb[l])
    bf16_t* Xn = l ? X0 : Xb;
    gemm_bt<<<dim3(8, MRP / 128), 256, 0, stream>>>(Hb,
        Fbf + (size_t)l * E_DIM * H_DIM, H_DIM,
        Fb + l * E_DIM, E_DIM, nullptr, 1,
        Xn, E_DIM, nullptr, 0L, 0, 0, 0);
    Xc = Xn;
  }
  // logits[1:] = X @ Dw^T + Db
  gemm_bt<<<dim3(VP / 128, MRP / 128), 256, 0, stream>>>(Xc, Dbf, H_DIM,
      Db, V_DIM, nullptr, 0,
      nullptr, 0, out, ST_V, 1, V_DIM, MR);

  (void)in_sizes; (void)n_in; (void)out_size; (void)ws_size;
}

// Round 2
// 1082.744 us; speedup vs baseline: 1.1082x; 1.1082x over previous
//
#include <hip/hip_runtime.h>
#include <hip/hip_bf16.h>
#include <cstdint>
#include <cstddef>

// Problem constants
#define T_DIM 128
#define B_DIM 64
#define E_DIM 1024
#define H_DIM 1024
#define V_DIM 10000
#define L_DIM 2
#define VP2   10240      // V padded to 80 tiles of 128
#define MROWS 8192       // T*B rows, t-major (row = t*64 + b) = 64 tiles exactly
#define WN    2097152    // L*H*E = 2^21 (per-weight-array element count)
#define WL    1048576    // per-layer weight stride (H*E)

typedef __bf16 bf16_t;
typedef bf16_t bf16x8 __attribute__((ext_vector_type(8)));
typedef bf16_t bf16x4 __attribute__((ext_vector_type(4)));
typedef float  f32x4  __attribute__((ext_vector_type(4)));

__device__ __forceinline__ void g2l16(const void* g, void* l) {
  __builtin_amdgcn_global_load_lds((const __attribute__((address_space(1))) void*)g,
                                   (__attribute__((address_space(3))) void*)l,
                                   16, 0, 0);
}

__device__ __forceinline__ float fast_tanh(float v) {
  v = fminf(15.f, fmaxf(-15.f, v));
  float e = __expf(2.f * v);
  return (e - 1.f) / (e + 1.f);
}

// C = A @ B^T (+bias[n]) (+Z two-section) (tanh?)
// Row semantics: t = row>>6, b = row&63 (t-major combined layout).
// Z (if set, N must be 1024): row<64 -> Z[row*1024+n] (HU section),
//                             else   -> Z[(64+(row&63))*1024+n] (aU section).
// outb: bf16 full-tile stores (scratch buffers, stride outb_stride).
// outf: fp32 stores at outf + t*stride_t + b*stride_b + n, guarded by
//       row<Mvalid && n<Nvalid.
// BNT>0: 1-D swizzled grid (gridDim.x = BMT*BNT, BMT%8==0): XCD-stripe
//        mapping — g&7 picks an 8-bm-tile stripe (2MB A resident per XCD L2),
//        bn swept outer. BNT==0: bn=blockIdx.x, bm=0, batch=blockIdx.y.
template<int BK>
__global__ __launch_bounds__(256)
void gemm_bt(const bf16_t* __restrict__ A, const bf16_t* __restrict__ Bm, int K,
             const float* __restrict__ bias, int Nvalid,
             const float* __restrict__ Z, int do_tanh,
             bf16_t* __restrict__ outb, int outb_stride,
             float* __restrict__ outf, long stride_t, int stride_b, int Mvalid,
             int BNT, long abatch, long bbatch, long biasbatch, long obatch)
{
  __shared__ alignas(16) bf16_t lA[128 * BK];
  __shared__ alignas(16) bf16_t lB[128 * BK];
  const int tid  = threadIdx.x;
  const int wid  = tid >> 6;
  const int lane = tid & 63;

  int bm, bn;
  if (BNT > 0) {
    int g   = blockIdx.x;
    int SM  = (gridDim.x / BNT) >> 3;   // bm tiles per XCD stripe
    int xcd = g & 7;
    int q   = g >> 3;
    bm = xcd * SM + (q % SM);
    bn = q / SM;
  } else {
    bn = blockIdx.x;
    bm = 0;
    int batch = blockIdx.y;
    A    += (size_t)batch * abatch;
    Bm   += (size_t)batch * bbatch;
    bias += (size_t)batch * biasbatch;
    if (outf) outf += (size_t)batch * obatch;
  }

  f32x4 zero = {0.f, 0.f, 0.f, 0.f};
  f32x4 acc[4][4];
#pragma unroll
  for (int i = 0; i < 4; ++i)
#pragma unroll
    for (int j = 0; j < 4; ++j) acc[i][j] = zero;

  // staging: chunks of 16B; chunk = (u*4+wid)*64 + lane  (wave-uniform LDS base)
  constexpr int CW    = BK / 8;            // 16B chunks per row
  constexpr int CALLS = (128 * BK / 8) / 256;
  const bf16_t* gA[CALLS];
  const bf16_t* gB[CALLS];
  int ldsoff[CALLS];
#pragma unroll
  for (int u = 0; u < CALLS; ++u) {
    int chunk = (u * 4 + wid) * 64 + lane;
    int row = chunk / CW, cc = chunk % CW;
    gA[u] = A  + (size_t)(bm * 128 + row) * K + cc * 8;
    gB[u] = Bm + (size_t)(bn * 128 + row) * K + cc * 8;
    ldsoff[u] = chunk * 16;
  }

  const int mrow = (wid >> 1) * 64;   // wave's 64x64 quadrant
  const int ncol = (wid & 1) * 64;
  const int fr = lane & 15;
  const int fq = (lane >> 4) * 16;    // byte offset of 8-elem k-chunk
  char* lAb = (char*)lA;
  char* lBb = (char*)lB;

  for (int k0 = 0; k0 < K; k0 += BK) {
    __syncthreads();
#pragma unroll
    for (int u = 0; u < CALLS; ++u) g2l16(gA[u] + k0, lAb + ldsoff[u]);
#pragma unroll
    for (int u = 0; u < CALLS; ++u) g2l16(gB[u] + k0, lBb + ldsoff[u]);
    __syncthreads();

#pragma unroll
    for (int kk = 0; kk < BK / 32; ++kk) {
      bf16x8 af[4], bfv[4];
#pragma unroll
      for (int t = 0; t < 4; ++t) {
        af[t]  = *(const bf16x8*)(lAb + (mrow + t * 16 + fr) * (2 * BK) + kk * 64 + fq);
        bfv[t] = *(const bf16x8*)(lBb + (ncol + t * 16 + fr) * (2 * BK) + kk * 64 + fq);
      }
#pragma unroll
      for (int tm = 0; tm < 4; ++tm)
#pragma unroll
        for (int tn = 0; tn < 4; ++tn)
          acc[tm][tn] = __builtin_amdgcn_mfma_f32_16x16x32_bf16(af[tm], bfv[tn], acc[tm][tn], 0, 0, 0);
    }
  }

  // epilogue: C/D layout col=lane&15, row=(lane>>4)*4+reg (m89-verified)
  const int rb = (lane >> 4) * 4;
  const int cb = lane & 15;
#pragma unroll
  for (int tm = 0; tm < 4; ++tm) {
#pragma unroll
    for (int tn = 0; tn < 4; ++tn) {
      const int col = bn * 128 + ncol + tn * 16 + cb;
      const float bv = (col < Nvalid) ? bias[col] : 0.f;
#pragma unroll
      for (int r = 0; r < 4; ++r) {
        const int row = bm * 128 + mrow + tm * 16 + rb + r;
        float v = acc[tm][tn][r] + bv;
        if (Z) {
          int zr = (row < 64) ? row : 64 + (row & 63);
          v += Z[zr * 1024 + col];
        }
        if (do_tanh) v = fast_tanh(v);
        if (outb) outb[(size_t)row * outb_stride + col] = (bf16_t)v;
        if (outf && row < Mvalid && col < Nvalid) {
          long o = (long)(row >> 6) * stride_t + (long)(row & 63) * stride_b + col;
          outf[o] = v;
        }
      }
    }
  }
}

// ---- vectorized conversion / gather kernels (x4) ----
__global__ void k_cvt3(const float* __restrict__ a, const float* __restrict__ b,
                       const float* __restrict__ c, bf16_t* __restrict__ da,
                       bf16_t* __restrict__ db, bf16_t* __restrict__ dc) {
  int i = blockIdx.x * 256 + threadIdx.x;   // < 3*WN/4
  int j = i << 2;
  int sel = j >> 21;
  int loc = j & (WN - 1);
  const float* s = (sel == 0) ? a : (sel == 1) ? b : c;
  bf16_t*      d = (sel == 0) ? da : (sel == 1) ? db : dc;
  f32x4 v = *(const f32x4*)(s + loc);
  bf16x4 o;
#pragma unroll
  for (int k = 0; k < 4; ++k) o[k] = (bf16_t)v[k];
  *(bf16x4*)(d + loc) = o;
}

__global__ void k_cvt_dw4(const float* __restrict__ s, bf16_t* __restrict__ d) {
  int i = blockIdx.x * 256 + threadIdx.x;   // < VP2*1024/4
  int j = i << 2;
  int r = j >> 10, c = j & 1023;
  f32x4 v = {0.f, 0.f, 0.f, 0.f};
  if (r < V_DIM) v = *(const f32x4*)(s + (size_t)r * 1024 + c);
  bf16x4 o;
#pragma unroll
  for (int k = 0; k < 4; ++k) o[k] = (bf16_t)v[k];
  *(bf16x4*)(d + j) = o;
}

__global__ void k_gather4(const int* __restrict__ inp, const float* __restrict__ etab,
                          bf16_t* __restrict__ X) {
  int i = blockIdx.x * 256 + threadIdx.x;   // < MROWS*1024/4
  int j = i << 2;
  int r = j >> 10, e = j & 1023;            // r = t*64+b == flat index into inp
  int idx = inp[r];
  f32x4 v = *(const f32x4*)(etab + (size_t)idx * 1024 + e);
  bf16x4 o;
#pragma unroll
  for (int k = 0; k < 4; ++k) o[k] = (bf16_t)v[k];
  *(bf16x4*)(X + j) = o;
}

__global__ void k_cvt_hidden4(const float* __restrict__ hid, bf16_t* __restrict__ d) {
  int i = blockIdx.x * 256 + threadIdx.x;   // < L*128*1024/4
  int j = i << 2;
  int l = j >> 17, r = (j >> 10) & 127, e = j & 1023;
  f32x4 v = {0.f, 0.f, 0.f, 0.f};
  if (r < B_DIM) v = *(const f32x4*)(hid + (size_t)(l * B_DIM + r) * 1024 + e);
  bf16x4 o;
#pragma unroll
  for (int k = 0; k < 4; ++k) o[k] = (bf16_t)v[k];
  *(bf16x4*)(d + j) = o;
}

extern "C" void kernel_launch(void* const* d_in, const int* in_sizes, int n_in,
                              void* d_out, int out_size, void* d_ws, size_t ws_size,
                              hipStream_t stream) {
  const int*   inp    = (const int*)  d_in[0];
  const float* hidden = (const float*)d_in[1];
  const float* etab   = (const float*)d_in[2];
  const float* Ww     = (const float*)d_in[3];
  const float* Wb     = (const float*)d_in[4];
  const float* Uw     = (const float*)d_in[5];
  const float* Ub     = (const float*)d_in[6];
  const float* Fw     = (const float*)d_in[7];
  const float* Fb     = (const float*)d_in[8];
  const float* Dw     = (const float*)d_in[9];
  const float* Db     = (const float*)d_in[10];
  float* out = (float*)d_out;

  // workspace carve (~66 MB)
  char* p = (char*)d_ws;
  auto carve = [&](size_t n) { char* r = p; p += (n + 255) & ~(size_t)255; return r; };
  bf16_t* Wbf  = (bf16_t*)carve((size_t)WN * 2);
  bf16_t* Ubf  = (bf16_t*)carve((size_t)WN * 2);
  bf16_t* Fbf  = (bf16_t*)carve((size_t)WN * 2);
  bf16_t* Dbf  = (bf16_t*)carve((size_t)VP2 * 1024 * 2);
  bf16_t* Xc   = (bf16_t*)carve((size_t)MROWS * 1024 * 2);
  bf16_t* Hc   = (bf16_t*)carve((size_t)MROWS * 1024 * 2);
  bf16_t* hidb = (bf16_t*)carve((size_t)L_DIM * 128 * 1024 * 2);
  bf16_t* h0b  = (bf16_t*)carve((size_t)128 * 1024 * 2);
  float*  Zbuf = (float*) carve((size_t)2 * 128 * 1024 * 4);  // [l][{HU:64, aU:64}][1024]
  float*  Z0 = Zbuf, * Z1 = Zbuf + 131072;

  float* hall = out + (size_t)T_DIM * B_DIM * V_DIM;
  const long ST_H = (long)L_DIM * B_DIM * H_DIM;   // 131072
  const long ST_V = (long)B_DIM * V_DIM;           // 640000

  // prep
  k_cvt3       <<<3 * WN / 4 / 256, 256, 0, stream>>>(Ww, Uw, Fw, Wbf, Ubf, Fbf);
  k_cvt_dw4    <<<VP2 * 1024 / 4 / 256, 256, 0, stream>>>(Dw, Dbf);
  k_gather4    <<<MROWS * 1024 / 4 / 256, 256, 0, stream>>>(inp, etab, Xc);
  k_cvt_hidden4<<<L_DIM * 128 * 1024 / 4 / 256, 256, 0, stream>>>(hidden, hidb);

  // step-0 chain (small, BK=64). HU for both layers batched via grid.y.
  gemm_bt<64><<<dim3(8, 2), 256, 0, stream>>>(hidb, Ubf, 1024,
      Ub, 1024, nullptr, 0, nullptr, 0,
      Zbuf, 0L, 1024, 64,
      0, (long)128 * 1024, (long)WL, 1024L, 131072L);

  for (int l = 0; l < L_DIM; ++l) {
    float* Zl = l ? Z1 : Z0;
    // h0_l = tanh(x0 @ Ww^T + Wb + HU_l)  (rows 0..63 valid; A = current X rows 0..127)
    gemm_bt<64><<<dim3(8, 1), 256, 0, stream>>>(Xc, Wbf + (size_t)l * WL, 1024,
        Wb + l * 1024, 1024, Zl, 1, h0b, 1024,
        nullptr, 0L, 0, 0, 0, 0, 0, 0, 0);
    // aU_l = h0_l @ Uw^T + Ub  -> Z section rows 64..127
    gemm_bt<64><<<dim3(8, 1), 256, 0, stream>>>(h0b, Ubf + (size_t)l * WL, 1024,
        Ub + l * 1024, 1024, nullptr, 0, nullptr, 0,
        Zl + 64 * 1024, 0L, 1024, 64, 0, 0, 0, 0, 0);
    // H = tanh(X @ Ww^T + Wb + Z)  (all t; t=0 uses HU section) -> Hc + hall
    gemm_bt<32><<<dim3(64 * 8), 256, 0, stream>>>(Xc, Wbf + (size_t)l * WL, 1024,
        Wb + l * 1024, 1024, Zl, 1, Hc, 1024,
        hall + (size_t)l * B_DIM * H_DIM, ST_H, 1024, MROWS,
        8, 0, 0, 0, 0);
    // X = tanh(H @ Fw^T + Fb)
    gemm_bt<32><<<dim3(64 * 8), 256, 0, stream>>>(Hc, Fbf + (size_t)l * WL, 1024,
        Fb + l * 1024, 1024, nullptr, 1, Xc, 1024,
        nullptr, 0L, 0, 0, 8, 0, 0, 0, 0);
  }

  // logits = X @ Dw^T + Db  (all t)
  gemm_bt<32><<<dim3(64 * 80), 256, 0, stream>>>(Xc, Dbf, 1024,
      Db, V_DIM, nullptr, 0, nullptr, 0,
      out, ST_V, V_DIM, MROWS,
      80, 0, 0, 0, 0);

  (void)in_sizes; (void)n_in; (void)out_size; (void)ws_size;
}